// Round 14
// baseline (243.665 us; speedup 1.0000x reference)
//
#include <hip/hip_runtime.h>
#include <hip/hip_bf16.h>

typedef unsigned short u16;
typedef short bf8 __attribute__((ext_vector_type(8)));   // 8 bf16 = one MFMA A/B frag (4 VGPR)
typedef float f4 __attribute__((ext_vector_type(4)));    // one MFMA C/D frag

#define N_EDGE   1600000
#define NTILE    50000          // 32-edge tiles
#define BLOCKS   256
#define WAVES    12
#define NTHREADS (WAVES * 64)   // 768
#define SLOTS    (BLOCKS * WAVES)

// ws layout (bytes): w1t[0,102400) w2t[102400,122880) b1t[122880,124160) nodes_bf[124160,...)
#define WS_W2_OFF   51200       // u16 elems
#define WS_B1_OFF   61440       // u16 elems (float* at byte 122880)
#define WS_STATIC_B 124160
#define SMEM_INT4   7760        // 124160 / 16

// RNE f32 -> bf16 (prep only)
__device__ __forceinline__ u16 f2bf(float x) {
  union { float f; unsigned u; } v; v.f = x;
  unsigned r = v.u + 0x7FFFu + ((v.u >> 16) & 1u);
  return (u16)(r >> 16);
}

// packed RNE cvt, PURE C++ — no inline asm anywhere in edge_mlp. The asm
// v_cvt_pk_bf16_f32 version miscompiles under any schedule perturbation
// (r5/r6/r7/r10/r12 all |out|~20-38 >> reachable ~14); the C++ form (r11)
// compiled correctly even under an aggressive pipeline restructure.
__device__ __forceinline__ unsigned pk2(float lo, float hi) {
  union { __hip_bfloat16 b[2]; unsigned u; } o;
  o.b[0] = __float2bfloat16(lo);
  o.b[1] = __float2bfloat16(hi);
  return o.u;
}

union bfu { uint4 u; bf8 v; };

// load 8 contiguous f32, convert -> bf8 frag
__device__ __forceinline__ bf8 cvt8r(const float* __restrict__ s) {
  const float4 v0 = *(const float4*)s;
  const float4 v1 = *(const float4*)(s + 4);
  bfu o;
  o.u.x = pk2(v0.x, v0.y); o.u.y = pk2(v0.z, v0.w);
  o.u.z = pk2(v1.x, v1.y); o.u.w = pk2(v1.z, v1.w);
  return o.v;
}

// same, nontemporal loads (read-once edge stream)
__device__ __forceinline__ bf8 cvt8r_nt(const float* __restrict__ s) {
  const f4 v0 = __builtin_nontemporal_load((const f4*)s);
  const f4 v1 = __builtin_nontemporal_load((const f4*)(s + 4));
  bfu o;
  o.u.x = pk2(v0[0], v0[1]); o.u.y = pk2(v0[2], v0[3]);
  o.u.z = pk2(v1[0], v1[1]); o.u.w = pk2(v1[2], v1[3]);
  return o.v;
}

// ---------------- prep (round-4 verbatim) ----------------
// w1t: 100 frags [p*10+sub*5+kk][lane][8], elem (lane=16g+l15, j):
//      -log2e * W1[k=32kk+8g+j][hcol=32p+8(l15>>2)+4sub+(l15&3)]   (hcol permutation!)
// w2t: 20 frags [p*2+am][lane][8]: W2[hcol=32p+8g+j][outcol=16am+l15]
// b1t: f32[320]: b1t[af*16+row] = -log2e * b1[32(af>>1)+8(row>>2)+4(af&1)+(row&3)]
// nodes_bf: [50000][64] bf16
__global__ void prep_kernel(const float* __restrict__ nodes,
                            const float* __restrict__ W1,
                            const float* __restrict__ b1,
                            const float* __restrict__ W2,
                            u16* __restrict__ w1t,
                            u16* __restrict__ w2t,
                            float* __restrict__ b1t,
                            u16* __restrict__ nodes_bf) {
  const int b = blockIdx.x, t = threadIdx.x;
  if (b < 200) {
    const int i = b * 256 + t;                 // 51200 w1 frag elems
    const int j = i & 7, lane = (i >> 3) & 63, f = i >> 9;
    const int kk = f % 5, sub = (f / 5) & 1, p = f / 10;
    const int g = lane >> 4, l15 = lane & 15;
    const int k = 32 * kk + 8 * g + j;
    const int hcol = 32 * p + 8 * (l15 >> 2) + 4 * sub + (l15 & 3);
    w1t[i] = f2bf(-1.44269504f * W1[k * 320 + hcol]);
  } else if (b < 240) {
    const int i = (b - 200) * 256 + t;         // 10240 w2 frag elems
    const int j = i & 7, lane = (i >> 3) & 63, f = i >> 9;
    const int am = f & 1, p = f >> 1;
    const int g = lane >> 4, l15 = lane & 15;
    w2t[i] = f2bf(W2[(32 * p + 8 * g + j) * 32 + 16 * am + l15]);
  } else if (b == 240) {
    for (int i = t; i < 320; i += 256) {
      const int af = i >> 4, row = i & 15;
      const int hcol = 32 * (af >> 1) + 8 * (row >> 2) + 4 * (af & 1) + (row & 3);
      b1t[i] = -1.44269504f * b1[hcol];
    }
  } else {
    const int i = (b - 241) * 256 + t;         // 800000 float4s of nodes
    const float4 v = ((const float4*)nodes)[i];
    ushort4 o;
    o.x = f2bf(v.x); o.y = f2bf(v.y); o.z = f2bf(v.z); o.w = f2bf(v.w);
    ((ushort4*)nodes_bf)[i] = o;
  }
}

// ---------------- fused edge MLP (r9 structure, C++ pk2, pinned occupancy) ----------------
// 256 blocks x 12 waves; W1/W2/b1 in LDS once. Each wave: 32-edge tiles, grid-strided.
// GEMM1: h^T[16 hcol x 32 edge] per (p,sub): A=W1 frag (LDS), B=feats frag (global gather, regs).
// GEMM2: out^T[32 x 32] += W2frag x pk2(sigmoid(h)) -- h stays in registers (layout-matched).
// Round-14 levers (both outside the proven failure mode):
//   (a) C++ pk2 everywhere — removes the miscompiling asm->MFMA dataflow (r11 proof).
//   (b) amdgpu_waves_per_eu(3,3) — LDS caps us at 3 waves/SIMD anyway; pinning the RA
//       target there grants the full ~170-reg budget so bf[] stays resident and W1/W2
//       ds_reads can hoist (r11's FETCH-doubling remat + r4/r9's 68-reg squeeze both
//       stem from the RA targeting unreachable 8-wave occupancy).
__launch_bounds__(NTHREADS)
__attribute__((amdgpu_waves_per_eu(3, 3)))
__global__ void edge_mlp(const float* __restrict__ edges,
                         const int*   __restrict__ senders,
                         const int*   __restrict__ receivers,
                         const float* __restrict__ nodes_f,
                         const u16*   __restrict__ nodes_bf,
                         const int4*  __restrict__ wsrc,   // staged block: w1t|w2t|b1t
                         const float* __restrict__ b2,
                         float* __restrict__ out,
                         int use_bf) {
  __shared__ __align__(16) int4 smem4[SMEM_INT4];
  const u16*   w1s = (const u16*)smem4;
  const u16*   w2s = w1s + WS_W2_OFF;
  const float* b1s = (const float*)(w1s + WS_B1_OFF);

  for (int i = threadIdx.x; i < SMEM_INT4; i += NTHREADS) smem4[i] = wsrc[i];
  __syncthreads();                       // the only barrier

  const int tid = threadIdx.x;
  const int lane = tid & 63;
  const int wid  = tid >> 6;
  const int l15  = lane & 15;
  const int g    = lane >> 4;

  f4 b2v[2];
  b2v[0] = *(const f4*)(b2 + 4 * g);
  b2v[1] = *(const f4*)(b2 + 16 + 4 * g);

  for (int t = blockIdx.x * WAVES + wid; t < NTILE; t += SLOTS) {
    const int e0 = t * 32;

    // indices for this wave's 32 edges (edge = e0 + 16*ef + l15)
    int es[2], er[2];
    es[0] = senders[e0 + l15];        es[1] = senders[e0 + 16 + l15];
    er[0] = receivers[e0 + l15];      er[1] = receivers[e0 + 16 + l15];

    // B-frags: feats[edge][k], k: 0-63 sender, 64-127 receiver, 128-159 edgefeat
    bf8 bf[5][2];
    #pragma unroll
    for (int ef = 0; ef < 2; ++ef) {
      if (use_bf) {
        const u16* sb = nodes_bf + es[ef] * 64;
        const u16* rb = nodes_bf + er[ef] * 64;
        bf[0][ef] = *(const bf8*)(sb + 8 * g);
        bf[1][ef] = *(const bf8*)(sb + 32 + 8 * g);
        bf[2][ef] = *(const bf8*)(rb + 8 * g);
        bf[3][ef] = *(const bf8*)(rb + 32 + 8 * g);
      } else {
        const float* sb = nodes_f + es[ef] * 64;
        const float* rb = nodes_f + er[ef] * 64;
        bf[0][ef] = cvt8r(sb + 8 * g);
        bf[1][ef] = cvt8r(sb + 32 + 8 * g);
        bf[2][ef] = cvt8r(rb + 8 * g);
        bf[3][ef] = cvt8r(rb + 32 + 8 * g);
      }
      bf[4][ef] = cvt8r_nt(edges + (e0 + 16 * ef + l15) * 32 + 8 * g);
    }

    f4 acc2[2][2];                    // [am][ef], init = b2
    acc2[0][0] = b2v[0]; acc2[0][1] = b2v[0];
    acc2[1][0] = b2v[1]; acc2[1][1] = b2v[1];

    #pragma unroll 2
    for (int p = 0; p < 10; ++p) {
      f4 h[2][2];                     // [sub][ef]
      #pragma unroll
      for (int sub = 0; sub < 2; ++sub) {
        const int af = 2 * p + sub;
        const f4 binit = *(const f4*)(b1s + af * 16 + 4 * g);
        h[sub][0] = binit;
        h[sub][1] = binit;
        #pragma unroll
        for (int kk = 0; kk < 5; ++kk) {
          const bf8 a = *(const bf8*)(w1s + ((p * 10 + sub * 5 + kk) * 64 + lane) * 8);
          h[sub][0] = __builtin_amdgcn_mfma_f32_16x16x32_bf16(a, bf[kk][0], h[sub][0], 0, 0, 0);
          h[sub][1] = __builtin_amdgcn_mfma_f32_16x16x32_bf16(a, bf[kk][1], h[sub][1], 0, 0, 0);
        }
      }
      // sigmoid (W1,b1 prescaled by -log2e): s = rcp(1 + exp2(z'))
      bf8 pb[2];
      #pragma unroll
      for (int ef = 0; ef < 2; ++ef) {
        f4 s0, s1;
        #pragma unroll
        for (int r = 0; r < 4; ++r) {
          s0[r] = __builtin_amdgcn_rcpf(1.0f + __builtin_amdgcn_exp2f(h[0][ef][r]));
          s1[r] = __builtin_amdgcn_rcpf(1.0f + __builtin_amdgcn_exp2f(h[1][ef][r]));
        }
        bfu o;
        o.u.x = pk2(s0[0], s0[1]); o.u.y = pk2(s0[2], s0[3]);
        o.u.z = pk2(s1[0], s1[1]); o.u.w = pk2(s1[2], s1[3]);
        pb[ef] = o.v;               // = GEMM2 B-frag, k' = 8g+j <-> hcol 32p+8g+j
      }
      #pragma unroll
      for (int am = 0; am < 2; ++am) {
        const bf8 wa = *(const bf8*)(w2s + ((p * 2 + am) * 64 + lane) * 8);
        acc2[am][0] = __builtin_amdgcn_mfma_f32_16x16x32_bf16(wa, pb[0], acc2[am][0], 0, 0, 0);
        acc2[am][1] = __builtin_amdgcn_mfma_f32_16x16x32_bf16(wa, pb[1], acc2[am][1], 0, 0, 0);
      }
    }

    // store out[edge][32]: C row = 4g+r = outcol-16am, col = l15 = edge-within-16ef
    // nontemporal: write-once stream, keep it from evicting nodes_bf in L2/L3
    #pragma unroll
    for (int am = 0; am < 2; ++am)
      #pragma unroll
      for (int ef = 0; ef < 2; ++ef)
        __builtin_nontemporal_store(acc2[am][ef],
            (f4*)(out + (e0 + 16 * ef + l15) * 32 + 16 * am + 4 * g));
  }
}

extern "C" void kernel_launch(void* const* d_in, const int* in_sizes, int n_in,
                              void* d_out, int out_size, void* d_ws, size_t ws_size,
                              hipStream_t stream) {
  const float* nodes     = (const float*)d_in[0];
  const float* edges     = (const float*)d_in[1];
  const int*   senders   = (const int*)d_in[2];
  const int*   receivers = (const int*)d_in[3];
  const float* W1        = (const float*)d_in[4];
  const float* b1        = (const float*)d_in[5];
  const float* W2        = (const float*)d_in[6];
  const float* b2        = (const float*)d_in[7];
  float* out             = (float*)d_out;

  u16*   w1t      = (u16*)d_ws;
  u16*   w2t      = w1t + WS_W2_OFF;
  float* b1t      = (float*)(w1t + WS_B1_OFF);
  u16*   nodes_bf = (u16*)((char*)d_ws + WS_STATIC_B);
  const int use_bf = (ws_size >= (size_t)(WS_STATIC_B + 6400000)) ? 1 : 0;

  const int prep_blocks = use_bf ? (241 + 3125) : 241;
  prep_kernel<<<prep_blocks, 256, 0, stream>>>(nodes, W1, b1, W2, w1t, w2t, b1t, nodes_bf);
  edge_mlp<<<BLOCKS, NTHREADS, 0, stream>>>(edges, senders, receivers, nodes, nodes_bf,
                                            (const int4*)d_ws, b2, out, use_bf);
}

// Round 15
// 229.189 us; speedup vs baseline: 1.0632x; 1.0632x over previous
//
#include <hip/hip_runtime.h>

typedef unsigned short u16;
typedef short bf8 __attribute__((ext_vector_type(8)));   // 8 bf16 = one MFMA A/B frag (4 VGPR)
typedef float f4 __attribute__((ext_vector_type(4)));    // one MFMA C/D frag

#define N_EDGE   1600000
#define NTILE    50000          // 32-edge tiles
#define BLOCKS   256
#define WAVES    12
#define NTHREADS (WAVES * 64)   // 768
#define SLOTS    (BLOCKS * WAVES)

// ws layout (bytes): w1t[0,102400) w2t[102400,122880) b1t[122880,124160) nodes_bf[124160,...)
#define WS_W2_OFF   51200       // u16 elems
#define WS_B1_OFF   61440       // u16 elems (float* at byte 122880)
#define WS_STATIC_B 124160
#define SMEM_INT4   7760        // 124160 / 16

// RNE f32 -> bf16 (prep only)
__device__ __forceinline__ u16 f2bf(float x) {
  union { float f; unsigned u; } v; v.f = x;
  unsigned r = v.u + 0x7FFFu + ((v.u >> 16) & 1u);
  return (u16)(r >> 16);
}

// packed cvt: bits[15:0]=bf16(lo), bits[31:16]=bf16(hi)
__device__ __forceinline__ unsigned pk2(float lo, float hi) {
  unsigned r;
  asm("v_cvt_pk_bf16_f32 %0, %1, %2" : "=v"(r) : "v"(lo), "v"(hi));
  return r;
}

union bfu { uint4 u; bf8 v; };

// load 8 contiguous f32, convert -> bf8 frag
__device__ __forceinline__ bf8 cvt8r(const float* __restrict__ s) {
  const float4 v0 = *(const float4*)s;
  const float4 v1 = *(const float4*)(s + 4);
  bfu o;
  o.u.x = pk2(v0.x, v0.y); o.u.y = pk2(v0.z, v0.w);
  o.u.z = pk2(v1.x, v1.y); o.u.w = pk2(v1.z, v1.w);
  return o.v;
}

// same, nontemporal loads (read-once edge stream; keep it out of L2/L3).
// NOTE: __builtin_nontemporal_load requires ext_vector types, not HIP float4 structs.
__device__ __forceinline__ bf8 cvt8r_nt(const float* __restrict__ s) {
  const f4 v0 = __builtin_nontemporal_load((const f4*)s);
  const f4 v1 = __builtin_nontemporal_load((const f4*)(s + 4));
  bfu o;
  o.u.x = pk2(v0[0], v0[1]); o.u.y = pk2(v0[2], v0[3]);
  o.u.z = pk2(v1[0], v1[1]); o.u.w = pk2(v1[2], v1[3]);
  return o.v;
}

// ---------------- prep (round-4 verbatim) ----------------
// w1t: 100 frags [p*10+sub*5+kk][lane][8], elem (lane=16g+l15, j):
//      -log2e * W1[k=32kk+8g+j][hcol=32p+8(l15>>2)+4sub+(l15&3)]   (hcol permutation!)
// w2t: 20 frags [p*2+am][lane][8]: W2[hcol=32p+8g+j][outcol=16am+l15]
// b1t: f32[320]: b1t[af*16+row] = -log2e * b1[32(af>>1)+8(row>>2)+4(af&1)+(row&3)]
// nodes_bf: [50000][64] bf16
__global__ void prep_kernel(const float* __restrict__ nodes,
                            const float* __restrict__ W1,
                            const float* __restrict__ b1,
                            const float* __restrict__ W2,
                            u16* __restrict__ w1t,
                            u16* __restrict__ w2t,
                            float* __restrict__ b1t,
                            u16* __restrict__ nodes_bf) {
  const int b = blockIdx.x, t = threadIdx.x;
  if (b < 200) {
    const int i = b * 256 + t;                 // 51200 w1 frag elems
    const int j = i & 7, lane = (i >> 3) & 63, f = i >> 9;
    const int kk = f % 5, sub = (f / 5) & 1, p = f / 10;
    const int g = lane >> 4, l15 = lane & 15;
    const int k = 32 * kk + 8 * g + j;
    const int hcol = 32 * p + 8 * (l15 >> 2) + 4 * sub + (l15 & 3);
    w1t[i] = f2bf(-1.44269504f * W1[k * 320 + hcol]);
  } else if (b < 240) {
    const int i = (b - 200) * 256 + t;         // 10240 w2 frag elems
    const int j = i & 7, lane = (i >> 3) & 63, f = i >> 9;
    const int am = f & 1, p = f >> 1;
    const int g = lane >> 4, l15 = lane & 15;
    w2t[i] = f2bf(W2[(32 * p + 8 * g + j) * 32 + 16 * am + l15]);
  } else if (b == 240) {
    for (int i = t; i < 320; i += 256) {
      const int af = i >> 4, row = i & 15;
      const int hcol = 32 * (af >> 1) + 8 * (row >> 2) + 4 * (af & 1) + (row & 3);
      b1t[i] = -1.44269504f * b1[hcol];
    }
  } else {
    const int i = (b - 241) * 256 + t;         // 800000 float4s of nodes
    const float4 v = ((const float4*)nodes)[i];
    ushort4 o;
    o.x = f2bf(v.x); o.y = f2bf(v.y); o.z = f2bf(v.z); o.w = f2bf(v.w);
    ((ushort4*)nodes_bf)[i] = o;
  }
}

// ---------------- fused edge MLP (round-9/13 verbatim — FINAL, FROZEN) ----------------
// 256 blocks x 12 waves; W1/W2/b1 in LDS once. Each wave: 32-edge tiles, grid-strided.
// GEMM1: h^T[16 hcol x 32 edge] per (p,sub): A=W1 frag (LDS), B=feats frag (global gather, regs).
// GEMM2: out^T[32 x 32] += W2frag x pk2(sigmoid(h)) -- h stays in registers (layout-matched).
//
// FINAL at ~232 us (verified r9, r13). Session ledger: 630 -> 533 -> 232 us via the
// persistent barrier-free single-LDS-image MFMA structure. Complete experiment matrix:
//   asm pk2 + THIS schedule        = 232 us, correct (r4/r9/r13, deterministic)
//   asm pk2 + any restructure      = corrupted output (r5/r6/r7/r10/r12: |out| 20-38
//                                    >> reachable bound ~14 — toolchain miscompile)
//   C++ pk2 (any schedule)         = correct but +12-74 us VALU cost (r11: 306, r14: 244)
//   occupancy attrs (wpe/lbounds)  = inert on allocation (VGPR stays 68) or fatal
//   nt-hints, setprio              = neutral / fatal
// Not a HW roofline (MfmaUtil 37%, VALUBusy 47%); the ~110 us overlap floor needs
// phase-overlap restructures this toolchain deterministically miscompiles. Frozen.
__launch_bounds__(NTHREADS, 3)
__global__ void edge_mlp(const float* __restrict__ edges,
                         const int*   __restrict__ senders,
                         const int*   __restrict__ receivers,
                         const float* __restrict__ nodes_f,
                         const u16*   __restrict__ nodes_bf,
                         const int4*  __restrict__ wsrc,   // staged block: w1t|w2t|b1t
                         const float* __restrict__ b2,
                         float* __restrict__ out,
                         int use_bf) {
  __shared__ __align__(16) int4 smem4[SMEM_INT4];
  const u16*   w1s = (const u16*)smem4;
  const u16*   w2s = w1s + WS_W2_OFF;
  const float* b1s = (const float*)(w1s + WS_B1_OFF);

  for (int i = threadIdx.x; i < SMEM_INT4; i += NTHREADS) smem4[i] = wsrc[i];
  __syncthreads();                       // the only barrier

  const int tid = threadIdx.x;
  const int lane = tid & 63;
  const int wid  = tid >> 6;
  const int l15  = lane & 15;
  const int g    = lane >> 4;

  f4 b2v[2];
  b2v[0] = *(const f4*)(b2 + 4 * g);
  b2v[1] = *(const f4*)(b2 + 16 + 4 * g);

  for (int t = blockIdx.x * WAVES + wid; t < NTILE; t += SLOTS) {
    const int e0 = t * 32;

    // indices for this wave's 32 edges (edge = e0 + 16*ef + l15)
    int es[2], er[2];
    es[0] = senders[e0 + l15];        es[1] = senders[e0 + 16 + l15];
    er[0] = receivers[e0 + l15];      er[1] = receivers[e0 + 16 + l15];

    // B-frags: feats[edge][k], k: 0-63 sender, 64-127 receiver, 128-159 edgefeat
    bf8 bf[5][2];
    #pragma unroll
    for (int ef = 0; ef < 2; ++ef) {
      if (use_bf) {
        const u16* sb = nodes_bf + es[ef] * 64;
        const u16* rb = nodes_bf + er[ef] * 64;
        bf[0][ef] = *(const bf8*)(sb + 8 * g);
        bf[1][ef] = *(const bf8*)(sb + 32 + 8 * g);
        bf[2][ef] = *(const bf8*)(rb + 8 * g);
        bf[3][ef] = *(const bf8*)(rb + 32 + 8 * g);
      } else {
        const float* sb = nodes_f + es[ef] * 64;
        const float* rb = nodes_f + er[ef] * 64;
        bf[0][ef] = cvt8r(sb + 8 * g);
        bf[1][ef] = cvt8r(sb + 32 + 8 * g);
        bf[2][ef] = cvt8r(rb + 8 * g);
        bf[3][ef] = cvt8r(rb + 32 + 8 * g);
      }
      bf[4][ef] = cvt8r_nt(edges + (e0 + 16 * ef + l15) * 32 + 8 * g);
    }

    f4 acc2[2][2];                    // [am][ef], init = b2
    acc2[0][0] = b2v[0]; acc2[0][1] = b2v[0];
    acc2[1][0] = b2v[1]; acc2[1][1] = b2v[1];

    #pragma unroll 2
    for (int p = 0; p < 10; ++p) {
      f4 h[2][2];                     // [sub][ef]
      #pragma unroll
      for (int sub = 0; sub < 2; ++sub) {
        const int af = 2 * p + sub;
        const f4 binit = *(const f4*)(b1s + af * 16 + 4 * g);
        h[sub][0] = binit;
        h[sub][1] = binit;
        #pragma unroll
        for (int kk = 0; kk < 5; ++kk) {
          const bf8 a = *(const bf8*)(w1s + ((p * 10 + sub * 5 + kk) * 64 + lane) * 8);
          h[sub][0] = __builtin_amdgcn_mfma_f32_16x16x32_bf16(a, bf[kk][0], h[sub][0], 0, 0, 0);
          h[sub][1] = __builtin_amdgcn_mfma_f32_16x16x32_bf16(a, bf[kk][1], h[sub][1], 0, 0, 0);
        }
      }
      // sigmoid (W1,b1 prescaled by -log2e): s = rcp(1 + exp2(z'))
      bf8 pb[2];
      #pragma unroll
      for (int ef = 0; ef < 2; ++ef) {
        f4 s0, s1;
        #pragma unroll
        for (int r = 0; r < 4; ++r) {
          s0[r] = __builtin_amdgcn_rcpf(1.0f + __builtin_amdgcn_exp2f(h[0][ef][r]));
          s1[r] = __builtin_amdgcn_rcpf(1.0f + __builtin_amdgcn_exp2f(h[1][ef][r]));
        }
        bfu o;
        o.u.x = pk2(s0[0], s0[1]); o.u.y = pk2(s0[2], s0[3]);
        o.u.z = pk2(s1[0], s1[1]); o.u.w = pk2(s1[2], s1[3]);
        pb[ef] = o.v;               // = GEMM2 B-frag, k' = 8g+j <-> hcol 32p+8g+j
      }
      #pragma unroll
      for (int am = 0; am < 2; ++am) {
        const bf8 wa = *(const bf8*)(w2s + ((p * 2 + am) * 64 + lane) * 8);
        acc2[am][0] = __builtin_amdgcn_mfma_f32_16x16x32_bf16(wa, pb[0], acc2[am][0], 0, 0, 0);
        acc2[am][1] = __builtin_amdgcn_mfma_f32_16x16x32_bf16(wa, pb[1], acc2[am][1], 0, 0, 0);
      }
    }

    // store out[edge][32]: C row = 4g+r = outcol-16am, col = l15 = edge-within-16ef
    // nontemporal: write-once stream, keep it from evicting nodes_bf in L2/L3
    #pragma unroll
    for (int am = 0; am < 2; ++am)
      #pragma unroll
      for (int ef = 0; ef < 2; ++ef)
        __builtin_nontemporal_store(acc2[am][ef],
            (f4*)(out + (e0 + 16 * ef + l15) * 32 + 16 * am + 4 * g));
  }
}

extern "C" void kernel_launch(void* const* d_in, const int* in_sizes, int n_in,
                              void* d_out, int out_size, void* d_ws, size_t ws_size,
                              hipStream_t stream) {
  const float* nodes     = (const float*)d_in[0];
  const float* edges     = (const float*)d_in[1];
  const int*   senders   = (const int*)d_in[2];
  const int*   receivers = (const int*)d_in[3];
  const float* W1        = (const float*)d_in[4];
  const float* b1        = (const float*)d_in[5];
  const float* W2        = (const float*)d_in[6];
  const float* b2        = (const float*)d_in[7];
  float* out             = (float*)d_out;

  u16*   w1t      = (u16*)d_ws;
  u16*   w2t      = w1t + WS_W2_OFF;
  float* b1t      = (float*)(w1t + WS_B1_OFF);
  u16*   nodes_bf = (u16*)((char*)d_ws + WS_STATIC_B);
  const int use_bf = (ws_size >= (size_t)(WS_STATIC_B + 6400000)) ? 1 : 0;

  const int prep_blocks = use_bf ? (241 + 3125) : 241;
  prep_kernel<<<prep_blocks, 256, 0, stream>>>(nodes, W1, b1, W2, w1t, w2t, b1t, nodes_bf);
  edge_mlp<<<BLOCKS, NTHREADS, 0, stream>>>(edges, senders, receivers, nodes, nodes_bf,
                                            (const int4*)d_ws, b2, out, use_bf);
}